// Round 2
// baseline (748.185 us; speedup 1.0000x reference)
//
#include <hip/hip_runtime.h>
#include <math.h>

#define N_TOK 2048
#define DM    512
#define NH    8
#define DH    64
#define HID   32

// ---------------- K0: U[n][j] = xyz[n] . W1[j]  (2048 x 32) ----------------
__global__ __launch_bounds__(256) void u_kernel(const float* __restrict__ xyz,
                                                const float* __restrict__ W1,
                                                float* __restrict__ U) {
    int idx = blockIdx.x * 256 + threadIdx.x;   // 65536 total
    int n = idx >> 5, j = idx & 31;
    const float* xp = xyz + n * 3;
    const float* wp = W1 + j * 3;
    U[idx] = xp[0] * wp[0] + xp[1] * wp[1] + xp[2] * wp[2];
}

// ---------------- generic C = A[2048x512] * B[512x512]^T + bias ----------------
__global__ __launch_bounds__(256) void gemm_awt(const float* __restrict__ A,
                                                const float* __restrict__ Bw,
                                                const float* __restrict__ bias,
                                                float* __restrict__ C) {
    __shared__ float As[32][68];
    __shared__ float Bs[32][68];
    const int n0 = blockIdx.x * 64;
    const int m0 = blockIdx.y * 64;
    const int t  = threadIdx.x;
    const int tx = t & 15, ty = t >> 4;

    float acc[4][4] = {};

    for (int k0 = 0; k0 < 512; k0 += 32) {
        #pragma unroll
        for (int i = 0; i < 2; ++i) {
            int fi  = i * 256 + t;
            int row = fi >> 3, k4 = fi & 7;
            float4 a = *(const float4*)(A + (size_t)(m0 + row) * 512 + k0 + k4 * 4);
            As[k4 * 4 + 0][row] = a.x; As[k4 * 4 + 1][row] = a.y;
            As[k4 * 4 + 2][row] = a.z; As[k4 * 4 + 3][row] = a.w;
            float4 b = *(const float4*)(Bw + (size_t)(n0 + row) * 512 + k0 + k4 * 4);
            Bs[k4 * 4 + 0][row] = b.x; Bs[k4 * 4 + 1][row] = b.y;
            Bs[k4 * 4 + 2][row] = b.z; Bs[k4 * 4 + 3][row] = b.w;
        }
        __syncthreads();
        #pragma unroll
        for (int k = 0; k < 32; ++k) {
            float4 a4 = *(const float4*)&As[k][ty * 4];
            float4 b4 = *(const float4*)&Bs[k][tx * 4];
            float av[4] = {a4.x, a4.y, a4.z, a4.w};
            float bv[4] = {b4.x, b4.y, b4.z, b4.w};
            #pragma unroll
            for (int i = 0; i < 4; ++i)
                #pragma unroll
                for (int j = 0; j < 4; ++j)
                    acc[i][j] = fmaf(av[i], bv[j], acc[i][j]);
        }
        __syncthreads();
    }

    float4 b4 = *(const float4*)(bias + n0 + tx * 4);
    float bb[4] = {b4.x, b4.y, b4.z, b4.w};
    #pragma unroll
    for (int i = 0; i < 4; ++i) {
        float4 o;
        o.x = acc[i][0] + bb[0]; o.y = acc[i][1] + bb[1];
        o.z = acc[i][2] + bb[2]; o.w = acc[i][3] + bb[3];
        *(float4*)(C + (size_t)(m0 + ty * 4 + i) * 512 + n0 + tx * 4) = o;
    }
}

// ---------------- K2: fused qk + head-shared bias + exp -> e-matrix ----------------
// Block: 8 q-rows x 64 m-cols x all 8 heads. 256 thr = 4 waves; wave w owns heads 2w,2w+1.
// No score LDS; softmax uses no-max-subtraction (scores bounded, exp-safe in fp32),
// normalization done by norm_kernel afterwards.
__global__ __launch_bounds__(256) void score_kernel(const float* __restrict__ q_ws,
                                                    const float* __restrict__ k_ws,
                                                    const float* __restrict__ U,
                                                    const float* __restrict__ b1,
                                                    const float* __restrict__ W2,
                                                    const float* __restrict__ b2,
                                                    float* __restrict__ attn_e) {
    __shared__ float s_q[8 * 512];    // 8 q rows, all heads
    __shared__ float s_ub[8 * 32];    // U[n]+b1 for the 8 rows

    const int t    = threadIdx.x;
    const int lane = t & 63;
    const int w    = __builtin_amdgcn_readfirstlane(t >> 6);
    const int m0   = blockIdx.x * 64;
    const int n0   = blockIdx.y * 8;
    const int m    = m0 + lane;
    const int h0   = w * 2;

    // stage 8 q rows: 4096 contiguous floats
    {
        const float4* src = (const float4*)(q_ws + (size_t)n0 * 512);
        float4* dst = (float4*)s_q;
        #pragma unroll
        for (int i = 0; i < 4; ++i) dst[i * 256 + t] = src[i * 256 + t];
    }
    {
        int r = t >> 5, j = t & 31;
        s_ub[t] = U[(n0 + r) * 32 + j] + b1[j];
    }

    // per-thread persistent registers
    float um[32];
    #pragma unroll
    for (int j4 = 0; j4 < 8; ++j4)
        *(float4*)&um[j4 * 4] = *(const float4*)(U + (size_t)m * 32 + j4 * 4);

    float kk0[64], kk1[64];
    #pragma unroll
    for (int d4 = 0; d4 < 16; ++d4) {
        *(float4*)&kk0[d4 * 4] = *(const float4*)(k_ws + (size_t)m * 512 + h0 * 64 + d4 * 4);
        *(float4*)&kk1[d4 * 4] = *(const float4*)(k_ws + (size_t)m * 512 + (h0 + 1) * 64 + d4 * 4);
    }
    const float b2h0 = b2[h0], b2h1 = b2[h0 + 1];
    __syncthreads();

    #pragma unroll 2
    for (int r = 0; r < 8; ++r) {
        // qk for two heads (q frags are wave-uniform LDS broadcasts)
        const float* qp0 = s_q + r * 512 + h0 * 64;
        float d0 = 0.f, d1 = 0.f;
        #pragma unroll
        for (int d4 = 0; d4 < 16; ++d4) {
            float4 qa = *(const float4*)(qp0 + d4 * 4);
            d0 = fmaf(qa.x, kk0[d4 * 4 + 0], d0);
            d0 = fmaf(qa.y, kk0[d4 * 4 + 1], d0);
            d0 = fmaf(qa.z, kk0[d4 * 4 + 2], d0);
            d0 = fmaf(qa.w, kk0[d4 * 4 + 3], d0);
            float4 qb = *(const float4*)(qp0 + 64 + d4 * 4);
            d1 = fmaf(qb.x, kk1[d4 * 4 + 0], d1);
            d1 = fmaf(qb.y, kk1[d4 * 4 + 1], d1);
            d1 = fmaf(qb.z, kk1[d4 * 4 + 2], d1);
            d1 = fmaf(qb.w, kk1[d4 * 4 + 3], d1);
        }
        // head-shared relu terms, contracted with W2 rows for both heads
        float bia0 = 0.f, bia1 = 0.f;
        const float* ubp = s_ub + r * 32;
        #pragma unroll
        for (int j = 0; j < 32; ++j) {
            float tj = fmaxf(ubp[j] - um[j], 0.f);
            bia0 = fmaf(W2[h0 * 32 + j], tj, bia0);        // uniform -> s_load, cached
            bia1 = fmaf(W2[(h0 + 1) * 32 + j], tj, bia1);
        }
        float e0 = __expf(d0 * 0.125f + bia0 + b2h0);
        float e1 = __expf(d1 * 0.125f + bia1 + b2h1);
        attn_e[((size_t)h0 * N_TOK + (n0 + r)) * N_TOK + m]       = e0;
        attn_e[((size_t)(h0 + 1) * N_TOK + (n0 + r)) * N_TOK + m] = e1;
    }
}

// ---------------- K2b: row normalize (sum + scale), one block per (h,row) ----------------
__global__ __launch_bounds__(256) void norm_kernel(float* __restrict__ attn) {
    __shared__ float s_part[4];
    const int t = threadIdx.x;
    float* row = attn + (size_t)blockIdx.x * N_TOK;
    float4 v0 = ((float4*)row)[t];
    float4 v1 = ((float4*)row)[t + 256];
    float s = v0.x + v0.y + v0.z + v0.w + v1.x + v1.y + v1.z + v1.w;
    #pragma unroll
    for (int off = 32; off; off >>= 1) s += __shfl_xor(s, off);
    if ((t & 63) == 0) s_part[t >> 6] = s;
    __syncthreads();
    float inv = 1.0f / (s_part[0] + s_part[1] + s_part[2] + s_part[3]);
    v0.x *= inv; v0.y *= inv; v0.z *= inv; v0.w *= inv;
    v1.x *= inv; v1.y *= inv; v1.z *= inv; v1.w *= inv;
    ((float4*)row)[t] = v0;
    ((float4*)row)[t + 256] = v1;
}

// ---------------- K3: out_h[n][h*64+d] = sum_m attn[h][n][m] * v[m][h*64+d] ----------------
__global__ __launch_bounds__(128) void pv_kernel(const float* __restrict__ attn,
                                                 const float* __restrict__ v_ws,
                                                 float* __restrict__ out_heads) {
    __shared__ float As[32][36];
    __shared__ float Bs[32][68];
    const int h  = blockIdx.z;
    const int n0 = blockIdx.y * 32;
    const int t  = threadIdx.x;
    const int tx = t & 15, ty = t >> 4;
    const float* Ah = attn + (size_t)h * N_TOK * N_TOK;

    float acc[4][4] = {};

    for (int k0 = 0; k0 < N_TOK; k0 += 32) {
        #pragma unroll
        for (int i = 0; i < 2; ++i) {
            int fi  = i * 128 + t;
            int row = fi >> 3, k4 = fi & 7;
            float4 a = *(const float4*)(Ah + (size_t)(n0 + row) * N_TOK + k0 + k4 * 4);
            As[k4 * 4 + 0][row] = a.x; As[k4 * 4 + 1][row] = a.y;
            As[k4 * 4 + 2][row] = a.z; As[k4 * 4 + 3][row] = a.w;
        }
        #pragma unroll
        for (int i = 0; i < 4; ++i) {
            int fi  = i * 128 + t;
            int row = fi >> 4, d4 = fi & 15;
            float4 b = *(const float4*)(v_ws + (size_t)(k0 + row) * 512 + h * 64 + d4 * 4);
            *(float4*)&Bs[row][d4 * 4] = b;
        }
        __syncthreads();
        #pragma unroll
        for (int k = 0; k < 32; ++k) {
            float4 a4 = *(const float4*)&As[k][ty * 4];
            float4 b4 = *(const float4*)&Bs[k][tx * 4];
            float av[4] = {a4.x, a4.y, a4.z, a4.w};
            float bv[4] = {b4.x, b4.y, b4.z, b4.w};
            #pragma unroll
            for (int i = 0; i < 4; ++i)
                #pragma unroll
                for (int j = 0; j < 4; ++j)
                    acc[i][j] = fmaf(av[i], bv[j], acc[i][j]);
        }
        __syncthreads();
    }

    #pragma unroll
    for (int i = 0; i < 4; ++i) {
        float4 o = {acc[i][0], acc[i][1], acc[i][2], acc[i][3]};
        *(float4*)(out_heads + (size_t)(n0 + ty * 4 + i) * 512 + h * 64 + tx * 4) = o;
    }
}

extern "C" void kernel_launch(void* const* d_in, const int* in_sizes, int n_in,
                              void* d_out, int out_size, void* d_ws, size_t ws_size,
                              hipStream_t stream) {
    const float* x   = (const float*)d_in[0];
    const float* xyz = (const float*)d_in[1];
    const float* Wq  = (const float*)d_in[2];
    const float* bq  = (const float*)d_in[3];
    const float* Wk  = (const float*)d_in[4];
    const float* bk  = (const float*)d_in[5];
    const float* Wv  = (const float*)d_in[6];
    const float* bv  = (const float*)d_in[7];
    const float* Wo  = (const float*)d_in[8];
    const float* bo  = (const float*)d_in[9];
    const float* W1  = (const float*)d_in[10];
    const float* b1  = (const float*)d_in[11];
    const float* W2  = (const float*)d_in[12];
    const float* b2  = (const float*)d_in[13];

    float* out      = (float*)d_out;
    float* attn_out = out + (size_t)N_TOK * DM;           // [8][2048][2048]

    float* ws = (float*)d_ws;
    float* qw = ws;                                        // [2048][512]
    float* kw = ws + 1048576;
    float* vw = ws + 2097152;
    float* U  = ws + 3145728;                              // [2048][32]
    float* oh = ws + 3145728 + 65536;                      // [2048][512]

    u_kernel<<<256, 256, 0, stream>>>(xyz, W1, U);
    gemm_awt<<<dim3(8, 32), 256, 0, stream>>>(x, Wq, bq, qw);
    gemm_awt<<<dim3(8, 32), 256, 0, stream>>>(x, Wk, bk, kw);
    gemm_awt<<<dim3(8, 32), 256, 0, stream>>>(x, Wv, bv, vw);

    // fused scores (all heads) -> e values
    score_kernel<<<dim3(32, 256), 256, 0, stream>>>(qw, kw, U, b1, W2, b2, attn_out);
    // row-wise softmax normalization
    norm_kernel<<<NH * N_TOK, 256, 0, stream>>>(attn_out);

    pv_kernel<<<dim3(1, 64, 8), 128, 0, stream>>>(attn_out, vw, oh);
    gemm_awt<<<dim3(8, 32), 256, 0, stream>>>(oh, Wo, bo, out);
}

// Round 6
// 514.182 us; speedup vs baseline: 1.4551x; 1.4551x over previous
//
#include <hip/hip_runtime.h>
#include <hip/hip_bf16.h>
#include <math.h>

#define N_TOK 2048
#define DM    512
#define NH    8
#define DH    64
#define HID   32

typedef __attribute__((ext_vector_type(8))) short short8;
typedef __attribute__((ext_vector_type(4))) float f32x4;
typedef unsigned short u16;

static __device__ __forceinline__ short bfbits(float f) {
    __hip_bfloat16 b = __float2bfloat16(f);
    return *reinterpret_cast<short*>(&b);
}

static __device__ __forceinline__ short8 cvt8(const float* p) {
    short8 r;
    #pragma unroll
    for (int i = 0; i < 8; ++i) r[i] = bfbits(p[i]);
    return r;
}

// ---------------- K0: U[n][j] = xyz[n] . W1[j]  (2048 x 32) ----------------
__global__ __launch_bounds__(256) void u_kernel(const float* __restrict__ xyz,
                                                const float* __restrict__ W1,
                                                float* __restrict__ U) {
    int idx = blockIdx.x * 256 + threadIdx.x;   // 65536 total
    int n = idx >> 5, j = idx & 31;
    const float* xp = xyz + n * 3;
    const float* wp = W1 + j * 3;
    U[idx] = xp[0] * wp[0] + xp[1] * wp[1] + xp[2] * wp[2];
}

// ---------------- MFMA GEMM: C[2048x512] = A(f32) x W(f32,[512out][512in])^T + bias ----
template<bool OUT_BF16>
__global__ __launch_bounds__(256) void mfma_gemm(const float* __restrict__ A,
                                                 const float* __restrict__ W,
                                                 const float* __restrict__ bias,
                                                 void* __restrict__ Cout) {
    const int t = threadIdx.x, lane = t & 63, w = t >> 6;
    const int l15 = lane & 15, lq = lane >> 4;
    const int row0 = blockIdx.x * 64 + (w & 1) * 32;
    const int col0 = blockIdx.y * 64 + (w >> 1) * 32;
    f32x4 acc[2][2] = {};

    for (int k0 = 0; k0 < 512; k0 += 32) {
        float av[2][8], bv[2][8];
        #pragma unroll
        for (int i = 0; i < 2; ++i) {
            const float* ap = A + (size_t)(row0 + i * 16 + l15) * 512 + k0 + lq * 8;
            *(float4*)&av[i][0] = *(const float4*)ap;
            *(float4*)&av[i][4] = *(const float4*)(ap + 4);
            const float* wp = W + (size_t)(col0 + i * 16 + l15) * 512 + k0 + lq * 8;
            *(float4*)&bv[i][0] = *(const float4*)wp;
            *(float4*)&bv[i][4] = *(const float4*)(wp + 4);
        }
        short8 af0 = cvt8(av[0]), af1 = cvt8(av[1]);
        short8 bf0 = cvt8(bv[0]), bf1 = cvt8(bv[1]);
        acc[0][0] = __builtin_amdgcn_mfma_f32_16x16x32_bf16(af0, bf0, acc[0][0], 0, 0, 0);
        acc[0][1] = __builtin_amdgcn_mfma_f32_16x16x32_bf16(af0, bf1, acc[0][1], 0, 0, 0);
        acc[1][0] = __builtin_amdgcn_mfma_f32_16x16x32_bf16(af1, bf0, acc[1][0], 0, 0, 0);
        acc[1][1] = __builtin_amdgcn_mfma_f32_16x16x32_bf16(af1, bf1, acc[1][1], 0, 0, 0);
    }

    #pragma unroll
    for (int i = 0; i < 2; ++i)
        #pragma unroll
        for (int j = 0; j < 2; ++j) {
            const int col = col0 + j * 16 + l15;
            const float bb = bias[col];
            #pragma unroll
            for (int r = 0; r < 4; ++r) {
                const int row = row0 + i * 16 + lq * 4 + r;
                float v = acc[i][j][r] + bb;
                if (OUT_BF16) ((u16*)Cout)[(size_t)row * 512 + col] = (u16)bfbits(v);
                else          ((float*)Cout)[(size_t)row * 512 + col] = v;
            }
        }
}

// ---------------- score: MFMA qk (all 8 heads) + shared-t bias + exp + rowsum ----------
// Writes f32 e-values (unnormalized softmax numerators) + per-row sums via atomics.
__global__ __launch_bounds__(256) void score_kernel(const u16* __restrict__ qb,
                                                    const u16* __restrict__ kb,
                                                    const float* __restrict__ U,
                                                    const float* __restrict__ b1,
                                                    const float* __restrict__ W2,
                                                    const float* __restrict__ b2,
                                                    float* __restrict__ eout,
                                                    float* __restrict__ rowsum) {
    __shared__ float s_ub[16 * 33];
    const int t = threadIdx.x, lane = t & 63, w = t >> 6;
    const int l15 = lane & 15, lq = lane >> 4;
    const int n0 = blockIdx.y * 16;
    const int mb = blockIdx.x * 256 + w * 64;

    for (int i = t; i < 512; i += 256)
        s_ub[(i >> 5) * 33 + (i & 31)] = U[(n0 + (i >> 5)) * 32 + (i & 31)] + b1[i & 31];
    __syncthreads();

    float rsum[8][4] = {};

    for (int mt = 0; mt < 4; ++mt) {
        const int m16 = mb + mt * 16;
        float um[32];
        #pragma unroll
        for (int j4 = 0; j4 < 8; ++j4)
            *(float4*)&um[j4 * 4] = *(const float4*)(U + (size_t)(m16 + l15) * 32 + j4 * 4);

        f32x4 acc[8] = {};
        const u16* qrow = qb + (size_t)(n0 + l15) * 512 + lq * 8;
        const u16* krow = kb + (size_t)(m16 + l15) * 512 + lq * 8;
        #pragma unroll
        for (int h = 0; h < 8; ++h) {
            short8 q0 = *(const short8*)(qrow + h * 64);
            short8 k0 = *(const short8*)(krow + h * 64);
            short8 q1 = *(const short8*)(qrow + h * 64 + 32);
            short8 k1 = *(const short8*)(krow + h * 64 + 32);
            acc[h] = __builtin_amdgcn_mfma_f32_16x16x32_bf16(q0, k0, acc[h], 0, 0, 0);
            acc[h] = __builtin_amdgcn_mfma_f32_16x16x32_bf16(q1, k1, acc[h], 0, 0, 0);
        }

        #pragma unroll
        for (int r = 0; r < 4; ++r) {
            const int nn = lq * 4 + r;
            float bias[8] = {};
            const float* ubp = s_ub + nn * 33;
            #pragma unroll 8
            for (int j = 0; j < 32; ++j) {
                float tj = fmaxf(ubp[j] - um[j], 0.f);
                #pragma unroll
                for (int h = 0; h < 8; ++h)
                    bias[h] = fmaf(W2[h * 32 + j], tj, bias[h]);
            }
            const size_t base = (size_t)(n0 + nn) * 2048 + m16 + l15;
            #pragma unroll
            for (int h = 0; h < 8; ++h) {
                float e = __expf(acc[h][r] * 0.125f + bias[h] + b2[h]);
                rsum[h][r] += e;
                eout[(size_t)h * 4194304 + base] = e;
            }
        }
    }

    #pragma unroll
    for (int h = 0; h < 8; ++h)
        #pragma unroll
        for (int r = 0; r < 4; ++r) {
            float v = rsum[h][r];
            v += __shfl_xor(v, 1);
            v += __shfl_xor(v, 2);
            v += __shfl_xor(v, 4);
            v += __shfl_xor(v, 8);
            if (l15 == 0) atomicAdd(&rowsum[h * 2048 + n0 + lq * 4 + r], v);
        }
}

// ---------------- pv_fp32 (R1-proven structure): normalize + attn write + fp32 PV ------
// Block: 32 n-rows x 64 d (one head), 128 threads, BK=32. grid (1, 64, 8).
// e and attn are the SAME buffer (read-then-write same address by same thread; no
// __restrict__ on them). Normalization folded into A-staging.
__global__ __launch_bounds__(128) void pv_fp32(const float* e,
                                               const float* __restrict__ rowsum,
                                               const float* __restrict__ vw,
                                               float* attn,
                                               float* __restrict__ oh) {
    __shared__ float As[32][36];
    __shared__ float Bs[32][68];
    __shared__ float s_inv[32];
    const int h  = blockIdx.z;
    const int n0 = blockIdx.y * 32;
    const int t  = threadIdx.x;
    const int tx = t & 15, ty = t >> 4;
    const size_t ebase = (size_t)h * N_TOK * N_TOK;

    if (t < 32) s_inv[t] = 1.0f / rowsum[h * N_TOK + n0 + t];
    __syncthreads();

    float acc[4][4] = {};

    for (int k0 = 0; k0 < N_TOK; k0 += 32) {
        #pragma unroll
        for (int i = 0; i < 2; ++i) {           // A: 32n x 32m = 256 float4
            int fi  = i * 128 + t;
            int row = fi >> 3, k4 = fi & 7;
            const size_t off = ebase + (size_t)(n0 + row) * N_TOK + k0 + k4 * 4;
            float4 a = *(const float4*)(e + off);
            const float inv = s_inv[row];
            a.x *= inv; a.y *= inv; a.z *= inv; a.w *= inv;
            *(float4*)(attn + off) = a;
            As[k4 * 4 + 0][row] = a.x; As[k4 * 4 + 1][row] = a.y;
            As[k4 * 4 + 2][row] = a.z; As[k4 * 4 + 3][row] = a.w;
        }
        #pragma unroll
        for (int i = 0; i < 4; ++i) {           // B: 32m x 64d = 512 float4
            int fi  = i * 128 + t;
            int row = fi >> 4, d4 = fi & 15;
            *(float4*)&Bs[row][d4 * 4] = *(const float4*)(vw + (size_t)(k0 + row) * 512 + h * 64 + d4 * 4);
        }
        __syncthreads();
        #pragma unroll
        for (int k = 0; k < 32; ++k) {
            float4 a4 = *(const float4*)&As[k][ty * 4];
            float4 b4 = *(const float4*)&Bs[k][tx * 4];
            float av[4] = {a4.x, a4.y, a4.z, a4.w};
            float bv[4] = {b4.x, b4.y, b4.z, b4.w};
            #pragma unroll
            for (int i = 0; i < 4; ++i)
                #pragma unroll
                for (int j = 0; j < 4; ++j)
                    acc[i][j] = fmaf(av[i], bv[j], acc[i][j]);
        }
        __syncthreads();
    }

    #pragma unroll
    for (int i = 0; i < 4; ++i) {
        float4 o = {acc[i][0], acc[i][1], acc[i][2], acc[i][3]};
        *(float4*)(oh + (size_t)(n0 + ty * 4 + i) * 512 + h * 64 + tx * 4) = o;
    }
}

// ---------------- fp32 VALU GEMM (final projection, precision-safe) ----------------
__global__ __launch_bounds__(256) void gemm_awt(const float* __restrict__ A,
                                                const float* __restrict__ Bw,
                                                const float* __restrict__ bias,
                                                float* __restrict__ C) {
    __shared__ float As[32][68];
    __shared__ float Bs[32][68];
    const int n0 = blockIdx.x * 64;
    const int m0 = blockIdx.y * 64;
    const int t  = threadIdx.x;
    const int tx = t & 15, ty = t >> 4;

    float acc[4][4] = {};

    for (int k0 = 0; k0 < 512; k0 += 32) {
        #pragma unroll
        for (int i = 0; i < 2; ++i) {
            int fi  = i * 256 + t;
            int row = fi >> 3, k4 = fi & 7;
            float4 a = *(const float4*)(A + (size_t)(m0 + row) * 512 + k0 + k4 * 4);
            As[k4 * 4 + 0][row] = a.x; As[k4 * 4 + 1][row] = a.y;
            As[k4 * 4 + 2][row] = a.z; As[k4 * 4 + 3][row] = a.w;
            float4 b = *(const float4*)(Bw + (size_t)(n0 + row) * 512 + k0 + k4 * 4);
            Bs[k4 * 4 + 0][row] = b.x; Bs[k4 * 4 + 1][row] = b.y;
            Bs[k4 * 4 + 2][row] = b.z; Bs[k4 * 4 + 3][row] = b.w;
        }
        __syncthreads();
        #pragma unroll
        for (int k = 0; k < 32; ++k) {
            float4 a4 = *(const float4*)&As[k][ty * 4];
            float4 b4 = *(const float4*)&Bs[k][tx * 4];
            float av[4] = {a4.x, a4.y, a4.z, a4.w};
            float bv[4] = {b4.x, b4.y, b4.z, b4.w};
            #pragma unroll
            for (int i = 0; i < 4; ++i)
                #pragma unroll
                for (int j = 0; j < 4; ++j)
                    acc[i][j] = fmaf(av[i], bv[j], acc[i][j]);
        }
        __syncthreads();
    }

    float4 b4 = *(const float4*)(bias + n0 + tx * 4);
    float bb[4] = {b4.x, b4.y, b4.z, b4.w};
    #pragma unroll
    for (int i = 0; i < 4; ++i) {
        float4 o;
        o.x = acc[i][0] + bb[0]; o.y = acc[i][1] + bb[1];
        o.z = acc[i][2] + bb[2]; o.w = acc[i][3] + bb[3];
        *(float4*)(C + (size_t)(m0 + ty * 4 + i) * 512 + n0 + tx * 4) = o;
    }
}

extern "C" void kernel_launch(void* const* d_in, const int* in_sizes, int n_in,
                              void* d_out, int out_size, void* d_ws, size_t ws_size,
                              hipStream_t stream) {
    const float* x   = (const float*)d_in[0];
    const float* xyz = (const float*)d_in[1];
    const float* Wq  = (const float*)d_in[2];
    const float* bq  = (const float*)d_in[3];
    const float* Wk  = (const float*)d_in[4];
    const float* bk  = (const float*)d_in[5];
    const float* Wv  = (const float*)d_in[6];
    const float* bv  = (const float*)d_in[7];
    const float* Wo  = (const float*)d_in[8];
    const float* bo  = (const float*)d_in[9];
    const float* W1  = (const float*)d_in[10];
    const float* b1  = (const float*)d_in[11];
    const float* W2  = (const float*)d_in[12];
    const float* b2  = (const float*)d_in[13];

    float* out      = (float*)d_out;
    float* attn_out = out + (size_t)N_TOK * DM;           // [8][2048][2048] f32

    char* wsb = (char*)d_ws;
    float* U      = (float*)wsb;                          // 262144 B
    float* rowsum = (float*)(wsb + 262144);               // 65536 B
    float* oh     = (float*)(wsb + 327680);               // 4 MiB
    u16*   qb     = (u16*)(wsb + 4521984);                // 2 MiB
    u16*   kb     = (u16*)(wsb + 6619136);                // 2 MiB
    float* vw     = (float*)(wsb + 8716288);              // 4 MiB, ends 12910592

    u_kernel<<<256, 256, 0, stream>>>(xyz, W1, U);
    mfma_gemm<true><<<dim3(32, 8), 256, 0, stream>>>(x, Wq, bq, qb);
    mfma_gemm<true><<<dim3(32, 8), 256, 0, stream>>>(x, Wk, bk, kb);
    mfma_gemm<false><<<dim3(32, 8), 256, 0, stream>>>(x, Wv, bv, vw);
    hipMemsetAsync(rowsum, 0, NH * N_TOK * sizeof(float), stream);

    // e-values (f32) into the attn region of d_out; rowsum via atomics
    score_kernel<<<dim3(8, 128), 256, 0, stream>>>(qb, kb, U, b1, W2, b2, attn_out, rowsum);
    // normalize in-place -> attn output, fp32 VALU PV -> oh
    pv_fp32<<<dim3(1, 64, 8), 128, 0, stream>>>(attn_out, rowsum, vw, attn_out, oh);

    gemm_awt<<<dim3(8, 32), 256, 0, stream>>>(oh, Wo, bo, out);
}